// Round 2
// baseline (2692.008 us; speedup 1.0000x reference)
//
#include <hip/hip_runtime.h>

typedef _Float16 half8 __attribute__((ext_vector_type(8)));
typedef float floatx4 __attribute__((ext_vector_type(4)));

#define B_   8
#define N_   4096
#define S_   2048
#define K_   64
#define CIN  64
#define HID_ 128
#define Q_   (B_*S_)

// ---------------- ws layout (bytes), total ~2.26 MB ----------------
#define WS_STATS 0u          // 512 u64 (sum0,sq0,sum1,sq1) = 4096
#define WS_CNTT  4096u       // int, padded
#define WS_W0T   4224u       // 128*96 f16 = 24576
#define WS_W1T   28800u      // 128*128 f16 = 32768
#define WS_W2T   61568u      // 32768
#define WS_SC0   94336u      // 128 f32
#define WS_SH0   94848u
#define WS_SC1   95360u
#define WS_SH1   95872u
#define WS_CNT   96384u      // 16384 int = 65536
#define WS_NBR   161920u     // 16384*64 u16 = 2097152
// end ~2259072

__device__ inline unsigned long long shfl_xor_u64(unsigned long long v, int m) {
    unsigned lo = __shfl_xor((unsigned)v, m);
    unsigned hi = __shfl_xor((unsigned)(v >> 32), m);
    return ((unsigned long long)hi << 32) | (unsigned long long)lo;
}

// ---------------------------------------------------------------- prep
__global__ __launch_bounds__(256) void k_prep(const float* __restrict__ W0,
        const float* __restrict__ W1, const float* __restrict__ W2,
        _Float16* __restrict__ w0t, _Float16* __restrict__ w1t, _Float16* __restrict__ w2t,
        unsigned long long* __restrict__ stats, int* __restrict__ cntT) {
    int t = blockIdx.x * 256 + threadIdx.x;
    if (t < 128 * 96) {                       // W0T[c][k], k padded 67->96 with 0
        int c = t / 96, k = t - c * 96;
        w0t[t] = (k < 67) ? (_Float16)W0[k * 128 + c] : (_Float16)0.f;
    } else if (t < 128 * 96 + 16384) {        // W1T[c][k]
        int u = t - 128 * 96; int c = u >> 7, k = u & 127;
        w1t[u] = (_Float16)W1[k * 128 + c];
    } else if (t < 128 * 96 + 32768) {        // W2T[c][k]
        int u = t - 128 * 96 - 16384; int c = u >> 7, k = u & 127;
        w2t[u] = (_Float16)W2[k * 128 + c];
    }
    if (t < 512) stats[t] = 0ULL;
    if (t == 0) *cntT = 0;
}

// ---------------------------------------------------------------- FPS
// 8 blocks (one per cloud) x 512 threads, 8 points/thread (blocked -> index-monotone).
// Bit-exact vs numpy: fp contract OFF, argmax first-index tie-break via packed u64.
__global__ __launch_bounds__(512) void k_fps(const float* __restrict__ pos,
        float* __restrict__ outCtr, float* __restrict__ outBatch) {
    __shared__ float sP[N_ * 3];
    __shared__ unsigned long long red[2][8];
    int b = blockIdx.x, tid = threadIdx.x;
    const float* P = pos + (size_t)b * N_ * 3;
    {
        const float4* src = (const float4*)P;
        float4* dst = (float4*)sP;
        for (int i = tid; i < 3072; i += 512) dst[i] = src[i];
    }
    float a[24];
    {
        const float4* vp = (const float4*)(P + tid * 24);
        #pragma unroll
        for (int v = 0; v < 6; v++) {
            float4 t4 = vp[v];
            a[v*4] = t4.x; a[v*4+1] = t4.y; a[v*4+2] = t4.z; a[v*4+3] = t4.w;
        }
    }
    float px[8], py[8], pz[8], md[8];
    #pragma unroll
    for (int j = 0; j < 8; j++) {
        px[j] = a[3*j]; py[j] = a[3*j+1]; pz[j] = a[3*j+2];
        md[j] = __builtin_inff();
    }
    __syncthreads();
    int last = 0;
    for (int i = 0; i < S_; i++) {
        float lx = sP[3*last], ly = sP[3*last+1], lz = sP[3*last+2];
        if (tid == 0) {
            int o = b * S_ + i;
            outCtr[o*3] = lx; outCtr[o*3+1] = ly; outCtr[o*3+2] = lz;
            outBatch[o] = (float)b;
        }
        unsigned long long best;
        {
            #pragma clang fp contract(off)
            float bv = -1.f; unsigned bi = 0;
            #pragma unroll
            for (int j = 0; j < 8; j++) {
                float dx = px[j] - lx, dy = py[j] - ly, dz = pz[j] - lz;
                float d = (dx * dx + dy * dy) + dz * dz;   // numpy eval order, no fma
                float m = fminf(md[j], d); md[j] = m;
                if (m > bv) { bv = m; bi = (unsigned)j; }  // strict > => first index wins
            }
            best = ((unsigned long long)__float_as_uint(bv) << 32)
                 | (unsigned long long)(0xFFFFFFFFu - (unsigned)(tid * 8) - bi);
        }
        #pragma unroll
        for (int o = 32; o; o >>= 1) {
            unsigned long long oth = shfl_xor_u64(best, o);
            if (oth > best) best = oth;
        }
        if ((tid & 63) == 0) red[i & 1][tid >> 6] = best;
        __syncthreads();   // double-buffered red => one barrier per iter is race-free
        unsigned long long g = red[i & 1][0];
        #pragma unroll
        for (int w = 1; w < 8; w++) {
            unsigned long long o2 = red[i & 1][w];
            if (o2 > g) g = o2;
        }
        last = (int)(0xFFFFFFFFu - (unsigned)g);
    }
}

// ---------------------------------------------------------------- radius-KNN (exact rank select)
__global__ __launch_bounds__(256) void k_nbr(const float* __restrict__ pos,
        const float* __restrict__ ctr, unsigned short* __restrict__ nbr,
        int* __restrict__ cnt, int* __restrict__ cntT) {
    __shared__ float cD[1024];
    __shared__ int   cI[1024];
    __shared__ int   cN;
    int q = blockIdx.x, tid = threadIdx.x;
    int b = q >> 11;
    if (tid == 0) cN = 0;
    __syncthreads();
    float cx = ctr[q*3], cy = ctr[q*3+1], cz = ctr[q*3+2];
    const float* P = pos + (size_t)b * N_ * 3;
    {
        #pragma clang fp contract(off)
        for (int j = tid; j < N_; j += 256) {
            float dx = cx - P[j*3], dy = cy - P[j*3+1], dz = cz - P[j*3+2];
            float d2 = (dx * dx + dy * dy) + dz * dz;
            if (d2 <= 0.04f) {                       // f32(0.2**2) boundary, exact
                int s = atomicAdd(&cN, 1);
                if (s < 1024) { cD[s] = d2; cI[s] = j; }
            }
        }
    }
    __syncthreads();
    int M = min(cN, 1024);
    int V = min(M, K_);
    for (int i = tid; i < M; i += 256) {
        float di = cD[i]; int ii = cI[i]; int r = 0;
        for (int j = 0; j < M; j++) {
            float dj = cD[j];
            r += (dj < di) || (dj == di && cI[j] < ii);   // stable top_k tie-break
        }
        if (r < K_) nbr[q * K_ + r] = (unsigned short)ii; // rank IS the slot: deterministic
    }
    if (tid == 0) { cnt[q] = V; atomicAdd(cntT, V); }
}

// ---------------------------------------------------------------- BN params
__global__ void k_bnparam(const unsigned long long* __restrict__ stats, const int* __restrict__ cntT,
        const float* __restrict__ g, const float* __restrict__ be,
        float* __restrict__ scale, float* __restrict__ shift) {
    int t = threadIdx.x;
    double c = (double)(*cntT);
    double mean = (double)(long long)stats[t] * (1.0 / 1048576.0) / c;
    double ex2  = (double)(long long)stats[128 + t] * (1.0 / 1048576.0) / c;
    double var = ex2 - mean * mean;
    if (var < 0.0) var = 0.0;
    double sc = (double)g[t] / sqrt(var + 1e-5);
    scale[t] = (float)sc;
    shift[t] = (float)((double)be[t] - mean * sc);
}

// ---------------------------------------------------------------- fused MLP pass (recompute pipeline)
// STAGE 0: gather+GEMM0 -> stats0          (~49 KB LDS, 3 blocks/CU)
// STAGE 1: ... +BN0/ReLU+GEMM1 -> stats1   (~85 KB LDS, 1 block/CU)
// STAGE 2: ... +BN1/ReLU+GEMM2 -> max->out (~118 KB LDS, 1 block/CU)
template<int STAGE>
__global__ __launch_bounds__(256) void k_mlp(const float* __restrict__ x,
        const float* __restrict__ pos, const float* __restrict__ ctr,
        const unsigned short* __restrict__ nbr, const int* __restrict__ cnt,
        const _Float16* __restrict__ w0t, const _Float16* __restrict__ w1t,
        const _Float16* __restrict__ w2t,
        const float* __restrict__ b0, const float* __restrict__ b1,
        const float* __restrict__ b2,
        const float* __restrict__ sc0, const float* __restrict__ sh0,
        const float* __restrict__ sc1, const float* __restrict__ sh1,
        unsigned long long* __restrict__ statsOut, float* __restrict__ outF) {
    __shared__ __align__(16) _Float16 sW0[128 * 104];
    __shared__ __align__(16) _Float16 sW1[(STAGE >= 1) ? 128 * 136 : 8];
    __shared__ __align__(16) _Float16 sW2[(STAGE >= 2) ? 128 * 136 : 8];
    __shared__ __align__(16) _Float16 sBuf[64 * 136];   // feat(104) / h'(136) stage
    __shared__ float sSum[(STAGE <= 1) ? 512 : 4];
    __shared__ float sSq [(STAGE <= 1) ? 512 : 4];
    __shared__ float sMax[(STAGE == 2) ? 512 : 4];
    __shared__ unsigned short sNbr[64];
    __shared__ float sB0v[128];
    __shared__ float sB1v[(STAGE >= 1) ? 128 : 4];
    __shared__ float sSc0[(STAGE >= 1) ? 128 : 4];
    __shared__ float sSh0[(STAGE >= 1) ? 128 : 4];
    __shared__ float sB2v[(STAGE >= 2) ? 128 : 4];
    __shared__ float sSc1[(STAGE >= 2) ? 128 : 4];
    __shared__ float sSh1[(STAGE >= 2) ? 128 : 4];

    int tid = threadIdx.x, wid = tid >> 6, lane = tid & 63;
    int lr = lane & 15, lq = lane >> 4;

    {   // stage W0T (stride 104 f16 = 52 dwords: conflict-spread)
        const unsigned* src = (const unsigned*)w0t;
        unsigned* dst = (unsigned*)sW0;
        for (int i = tid; i < 6144; i += 256) { int r = i / 48, c = i - r * 48; dst[r*52 + c] = src[i]; }
    }
    if constexpr (STAGE >= 1) {
        const unsigned* src = (const unsigned*)w1t;
        unsigned* dst = (unsigned*)sW1;
        for (int i = tid; i < 8192; i += 256) { int r = i >> 6, c = i & 63; dst[r*68 + c] = src[i]; }
    }
    if constexpr (STAGE >= 2) {
        const unsigned* src = (const unsigned*)w2t;
        unsigned* dst = (unsigned*)sW2;
        for (int i = tid; i < 8192; i += 256) { int r = i >> 6, c = i & 63; dst[r*68 + c] = src[i]; }
    }
    if (tid < 128) {
        sB0v[tid] = b0[tid];
        if constexpr (STAGE >= 1) { sB1v[tid] = b1[tid]; sSc0[tid] = sc0[tid]; sSh0[tid] = sh0[tid]; }
        if constexpr (STAGE >= 2) { sB2v[tid] = b2[tid]; sSc1[tid] = sc1[tid]; sSh1[tid] = sh1[tid]; }
    }
    if constexpr (STAGE <= 1)
        for (int i = tid; i < 512; i += 256) { sSum[i] = 0.f; sSq[i] = 0.f; }

    for (int qq = 0; qq < 8; qq++) {
        int q = blockIdx.x * 8 + qq;
        int b = q >> 11;
        __syncthreads();                    // prior-iter sBuf readers done
        int n = cnt[q];
        if (tid < 64) sNbr[tid] = nbr[q * K_ + tid];
        __syncthreads();
        {   // gather x_j -> feat cols 0..63 (f16), zero rows >= n
            int row = tid >> 2, c4 = (tid & 3) * 16;
            half8 o0, o1;
            #pragma unroll
            for (int e = 0; e < 8; e++) { o0[e] = (_Float16)0.f; o1[e] = (_Float16)0.f; }
            if (row < n) {
                const float4* xr = (const float4*)(x + ((size_t)b * N_ + sNbr[row]) * CIN + c4);
                float4 v0 = xr[0], v1 = xr[1], v2 = xr[2], v3 = xr[3];
                o0[0]=(_Float16)v0.x; o0[1]=(_Float16)v0.y; o0[2]=(_Float16)v0.z; o0[3]=(_Float16)v0.w;
                o0[4]=(_Float16)v1.x; o0[5]=(_Float16)v1.y; o0[6]=(_Float16)v1.z; o0[7]=(_Float16)v1.w;
                o1[0]=(_Float16)v2.x; o1[1]=(_Float16)v2.y; o1[2]=(_Float16)v2.z; o1[3]=(_Float16)v2.w;
                o1[4]=(_Float16)v3.x; o1[5]=(_Float16)v3.y; o1[6]=(_Float16)v3.z; o1[7]=(_Float16)v3.w;
            }
            *(half8*)&sBuf[row * 104 + c4]     = o0;
            *(half8*)&sBuf[row * 104 + c4 + 8] = o1;
        }
        if (tid < 64) {   // cols 64..66 = pos_j - ctr, 67..95 = 0
            half8 z, o;
            #pragma unroll
            for (int e = 0; e < 8; e++) { z[e] = (_Float16)0.f; o[e] = (_Float16)0.f; }
            if (tid < n) {
                int j = sNbr[tid];
                float cx = ctr[q*3], cy = ctr[q*3+1], cz = ctr[q*3+2];
                const float* pj = pos + ((size_t)b * N_ + j) * 3;
                o[0] = (_Float16)(pj[0] - cx); o[1] = (_Float16)(pj[1] - cy); o[2] = (_Float16)(pj[2] - cz);
            }
            *(half8*)&sBuf[tid * 104 + 64] = o;
            *(half8*)&sBuf[tid * 104 + 72] = z;
            *(half8*)&sBuf[tid * 104 + 80] = z;
            *(half8*)&sBuf[tid * 104 + 88] = z;
        }
        __syncthreads();

        // ---- GEMM0: K=96
        floatx4 acc[8];
        #pragma unroll
        for (int nt = 0; nt < 8; nt++)
            #pragma unroll
            for (int r = 0; r < 4; r++) acc[nt][r] = 0.f;
        #pragma unroll
        for (int ks = 0; ks < 3; ks++) {
            half8 av = *(const half8*)&sBuf[(wid * 16 + lr) * 104 + ks * 32 + lq * 8];
            #pragma unroll
            for (int nt = 0; nt < 8; nt++) {
                half8 bv = *(const half8*)&sW0[(nt * 16 + lr) * 104 + ks * 32 + lq * 8];
                acc[nt] = __builtin_amdgcn_mfma_f32_16x16x32_f16(av, bv, acc[nt], 0, 0, 0);
            }
        }
        __syncthreads();                    // all waves done reading feat
        int r0 = wid * 16 + lq * 4;

        if constexpr (STAGE == 0) {
            #pragma unroll
            for (int nt = 0; nt < 8; nt++) {
                int col = nt * 16 + lr;
                float bias = sB0v[col];
                float s1 = 0.f, s2 = 0.f;
                #pragma unroll
                for (int r = 0; r < 4; r++) {
                    float v = acc[nt][r] + bias;
                    if (r0 + r < n) { s1 += v; s2 += v * v; }
                }
                s1 += __shfl_xor(s1, 16); s1 += __shfl_xor(s1, 32);
                s2 += __shfl_xor(s2, 16); s2 += __shfl_xor(s2, 32);
                if (lq == 0) { sSum[wid * 128 + col] += s1; sSq[wid * 128 + col] += s2; }
            }
        } else {
            // BN0 + ReLU -> f16 A-matrix for GEMM1
            #pragma unroll
            for (int nt = 0; nt < 8; nt++) {
                int col = nt * 16 + lr;
                float bias = sB0v[col], s = sSc0[col], t2 = sSh0[col];
                #pragma unroll
                for (int r = 0; r < 4; r++) {
                    float v = (acc[nt][r] + bias) * s + t2;
                    sBuf[(r0 + r) * 136 + col] = (_Float16)fmaxf(v, 0.f);
                }
            }
            __syncthreads();
            // ---- GEMM1: K=128
            #pragma unroll
            for (int nt = 0; nt < 8; nt++)
                #pragma unroll
                for (int r = 0; r < 4; r++) acc[nt][r] = 0.f;
            #pragma unroll
            for (int ks = 0; ks < 4; ks++) {
                half8 av = *(const half8*)&sBuf[(wid * 16 + lr) * 136 + ks * 32 + lq * 8];
                #pragma unroll
                for (int nt = 0; nt < 8; nt++) {
                    half8 bv = *(const half8*)&sW1[(nt * 16 + lr) * 136 + ks * 32 + lq * 8];
                    acc[nt] = __builtin_amdgcn_mfma_f32_16x16x32_f16(av, bv, acc[nt], 0, 0, 0);
                }
            }
            __syncthreads();

            if constexpr (STAGE == 1) {
                #pragma unroll
                for (int nt = 0; nt < 8; nt++) {
                    int col = nt * 16 + lr;
                    float bias = sB1v[col];
                    float s1 = 0.f, s2 = 0.f;
                    #pragma unroll
                    for (int r = 0; r < 4; r++) {
                        float v = acc[nt][r] + bias;
                        if (r0 + r < n) { s1 += v; s2 += v * v; }
                    }
                    s1 += __shfl_xor(s1, 16); s1 += __shfl_xor(s1, 32);
                    s2 += __shfl_xor(s2, 16); s2 += __shfl_xor(s2, 32);
                    if (lq == 0) { sSum[wid * 128 + col] += s1; sSq[wid * 128 + col] += s2; }
                }
            } else {
                // BN1 + ReLU -> f16 A-matrix for GEMM2
                #pragma unroll
                for (int nt = 0; nt < 8; nt++) {
                    int col = nt * 16 + lr;
                    float bias = sB1v[col], s = sSc1[col], t2 = sSh1[col];
                    #pragma unroll
                    for (int r = 0; r < 4; r++) {
                        float v = (acc[nt][r] + bias) * s + t2;
                        sBuf[(r0 + r) * 136 + col] = (_Float16)fmaxf(v, 0.f);
                    }
                }
                __syncthreads();
                // ---- GEMM2: K=128
                #pragma unroll
                for (int nt = 0; nt < 8; nt++)
                    #pragma unroll
                    for (int r = 0; r < 4; r++) acc[nt][r] = 0.f;
                #pragma unroll
                for (int ks = 0; ks < 4; ks++) {
                    half8 av = *(const half8*)&sBuf[(wid * 16 + lr) * 136 + ks * 32 + lq * 8];
                    #pragma unroll
                    for (int nt = 0; nt < 8; nt++) {
                        half8 bv = *(const half8*)&sW2[(nt * 16 + lr) * 136 + ks * 32 + lq * 8];
                        acc[nt] = __builtin_amdgcn_mfma_f32_16x16x32_f16(av, bv, acc[nt], 0, 0, 0);
                    }
                }
                // masked max -> out
                #pragma unroll
                for (int nt = 0; nt < 8; nt++) {
                    int col = nt * 16 + lr;
                    float bias = sB2v[col];
                    float m = -__builtin_inff();
                    #pragma unroll
                    for (int r = 0; r < 4; r++)
                        if (r0 + r < n) m = fmaxf(m, acc[nt][r] + bias);
                    m = fmaxf(m, __shfl_xor(m, 16));
                    m = fmaxf(m, __shfl_xor(m, 32));
                    if (lq == 0) sMax[wid * 128 + col] = m;
                }
                __syncthreads();
                if (tid < 128) {
                    float m = fmaxf(fmaxf(sMax[tid], sMax[128 + tid]),
                                    fmaxf(sMax[256 + tid], sMax[384 + tid]));
                    outF[(size_t)q * 128 + tid] = m;
                }
            }
        }
    }
    if constexpr (STAGE <= 1) {
        __syncthreads();
        if (tid < 128) {   // fixed-point (2^20) i64 atomics: fast + deterministic
            float t1 = sSum[tid] + sSum[128 + tid] + sSum[256 + tid] + sSum[384 + tid];
            float t2 = sSq[tid] + sSq[128 + tid] + sSq[256 + tid] + sSq[384 + tid];
            atomicAdd(&statsOut[tid],       (unsigned long long)(long long)llrintf(t1 * 1048576.f));
            atomicAdd(&statsOut[128 + tid], (unsigned long long)(long long)llrintf(t2 * 1048576.f));
        }
    }
}

// ---------------------------------------------------------------- launch
extern "C" void kernel_launch(void* const* d_in, const int* in_sizes, int n_in,
                              void* d_out, int out_size, void* d_ws, size_t ws_size,
                              hipStream_t stream) {
    const float* x   = (const float*)d_in[0];
    const float* pos = (const float*)d_in[1];
    const float* W0  = (const float*)d_in[3];
    const float* b0  = (const float*)d_in[4];
    const float* g0  = (const float*)d_in[5];
    const float* be0 = (const float*)d_in[6];
    const float* W1  = (const float*)d_in[7];
    const float* b1  = (const float*)d_in[8];
    const float* g1  = (const float*)d_in[9];
    const float* be1 = (const float*)d_in[10];
    const float* W2  = (const float*)d_in[11];
    const float* b2  = (const float*)d_in[12];

    char* ws = (char*)d_ws;
    unsigned long long* stats = (unsigned long long*)(ws + WS_STATS);
    int* cntT = (int*)(ws + WS_CNTT);
    _Float16* w0t = (_Float16*)(ws + WS_W0T);
    _Float16* w1t = (_Float16*)(ws + WS_W1T);
    _Float16* w2t = (_Float16*)(ws + WS_W2T);
    float* sc0 = (float*)(ws + WS_SC0);
    float* sh0 = (float*)(ws + WS_SH0);
    float* sc1 = (float*)(ws + WS_SC1);
    float* sh1 = (float*)(ws + WS_SH1);
    int* cnt = (int*)(ws + WS_CNT);
    unsigned short* nbr = (unsigned short*)(ws + WS_NBR);

    float* outF = (float*)d_out;                  // [16384,128]
    float* outCtr = (float*)d_out + 2097152;      // [16384,3]
    float* outBatch = (float*)d_out + 2146304;    // [16384]

    k_prep<<<176, 256, 0, stream>>>(W0, W1, W2, w0t, w1t, w2t, stats, cntT);
    k_fps<<<B_, 512, 0, stream>>>(pos, outCtr, outBatch);
    k_nbr<<<Q_, 256, 0, stream>>>(pos, outCtr, nbr, cnt, cntT);
    k_mlp<0><<<Q_/8, 256, 0, stream>>>(x, pos, outCtr, nbr, cnt, w0t, w1t, w2t,
            b0, b1, b2, sc0, sh0, sc1, sh1, stats, outF);
    k_bnparam<<<1, 128, 0, stream>>>(stats, cntT, g0, be0, sc0, sh0);
    k_mlp<1><<<Q_/8, 256, 0, stream>>>(x, pos, outCtr, nbr, cnt, w0t, w1t, w2t,
            b0, b1, b2, sc0, sh0, sc1, sh1, stats + 256, outF);
    k_bnparam<<<1, 128, 0, stream>>>(stats + 256, cntT, g1, be1, sc1, sh1);
    k_mlp<2><<<Q_/8, 256, 0, stream>>>(x, pos, outCtr, nbr, cnt, w0t, w1t, w2t,
            b0, b1, b2, sc0, sh0, sc1, sh1, stats, outF);
}

// Round 3
// 2386.636 us; speedup vs baseline: 1.1280x; 1.1280x over previous
//
#include <hip/hip_runtime.h>

typedef _Float16 half8 __attribute__((ext_vector_type(8)));
typedef float floatx4 __attribute__((ext_vector_type(4)));

#define B_   8
#define N_   4096
#define S_   2048
#define K_   64
#define CIN  64
#define HID_ 128
#define Q_   (B_*S_)

// ---------------- ws layout (bytes), total ~2.26 MB ----------------
#define WS_STATS 0u          // 512 u64 (sum0,sq0,sum1,sq1) = 4096
#define WS_CNTT  4096u       // int, padded
#define WS_W0T   4224u       // 128*96 f16 = 24576
#define WS_W1T   28800u      // 128*128 f16 = 32768
#define WS_W2T   61568u      // 32768
#define WS_SC0   94336u      // 128 f32
#define WS_SH0   94848u
#define WS_SC1   95360u
#define WS_SH1   95872u
#define WS_CNT   96384u      // 16384 int = 65536
#define WS_NBR   161920u     // 16384*64 u16 = 2097152
// end ~2259072

// ---------------------------------------------------------------- prep
__global__ __launch_bounds__(256) void k_prep(const float* __restrict__ W0,
        const float* __restrict__ W1, const float* __restrict__ W2,
        _Float16* __restrict__ w0t, _Float16* __restrict__ w1t, _Float16* __restrict__ w2t,
        unsigned long long* __restrict__ stats, int* __restrict__ cntT) {
    int t = blockIdx.x * 256 + threadIdx.x;
    if (t < 128 * 96) {                       // W0T[c][k], k padded 67->96 with 0
        int c = t / 96, k = t - c * 96;
        w0t[t] = (k < 67) ? (_Float16)W0[k * 128 + c] : (_Float16)0.f;
    } else if (t < 128 * 96 + 16384) {        // W1T[c][k]
        int u = t - 128 * 96; int c = u >> 7, k = u & 127;
        w1t[u] = (_Float16)W1[k * 128 + c];
    } else if (t < 128 * 96 + 32768) {        // W2T[c][k]
        int u = t - 128 * 96 - 16384; int c = u >> 7, k = u & 127;
        w2t[u] = (_Float16)W2[k * 128 + c];
    }
    if (t < 512) stats[t] = 0ULL;
    if (t == 0) *cntT = 0;
}

// ---------------------------------------------------------------- FPS
// 8 blocks x 256 threads, 16 pts/thread (blocked -> index-monotone lanes).
// Critical-path design: NO global stores in the loop (no vmcnt drain before
// s_barrier); DPP wave-reduce (VALU latency) instead of ds_bpermute shuffles;
// ONE barrier/iter with double-buffered cross-wave slots.
// Bit-exact vs numpy: fp contract OFF, numpy eval order, packed-u64 argmax
// with first-index tie-break.
template<int CTRL>
__device__ inline unsigned long long dpp64(unsigned long long v) {
    int lo = (int)(unsigned)v, hi = (int)(unsigned)(v >> 32);
    int nlo = __builtin_amdgcn_update_dpp(lo, lo, CTRL, 0xF, 0xF, false);
    int nhi = __builtin_amdgcn_update_dpp(hi, hi, CTRL, 0xF, 0xF, false);
    return ((unsigned long long)(unsigned)nhi << 32) | (unsigned long long)(unsigned)nlo;
}
__device__ inline unsigned long long u64max(unsigned long long a, unsigned long long b) {
    return (b > a) ? b : a;
}

__global__ __launch_bounds__(256) void k_fps(const float* __restrict__ pos,
        float* __restrict__ outCtr, float* __restrict__ outBatch) {
    __shared__ __align__(16) float4 sP4[N_];                  // 64 KB
    __shared__ __align__(16) unsigned long long red[2][4];
    __shared__ unsigned short sSeq[S_];                       // 4 KB
    int b = blockIdx.x, tid = threadIdx.x;
    const float* P = pos + (size_t)b * N_ * 3;

    float px[16], py[16], pz[16], md[16];
    {
        const float4* vp = (const float4*)(P + tid * 48);
        float a[48];
        #pragma unroll
        for (int v = 0; v < 12; v++) {
            float4 t4 = vp[v];
            a[v*4] = t4.x; a[v*4+1] = t4.y; a[v*4+2] = t4.z; a[v*4+3] = t4.w;
        }
        #pragma unroll
        for (int j = 0; j < 16; j++) {
            px[j] = a[3*j]; py[j] = a[3*j+1]; pz[j] = a[3*j+2];
            md[j] = __builtin_inff();
            sP4[tid * 16 + j] = make_float4(px[j], py[j], pz[j], 0.f);
        }
    }
    __syncthreads();

    int last = 0;
    for (int i = 0; i < S_; i++) {
        float4 cc = sP4[last];                       // broadcast ds_read_b128
        if (tid == (i & 255)) sSeq[i] = (unsigned short)last;
        unsigned long long best;
        {
            #pragma clang fp contract(off)
            float bv = -1.f; unsigned bi = 0;
            #pragma unroll
            for (int j = 0; j < 16; j++) {
                float dx = px[j] - cc.x, dy = py[j] - cc.y, dz = pz[j] - cc.z;
                float d = (dx * dx + dy * dy) + dz * dz;   // numpy order, no fma
                float m = fminf(md[j], d); md[j] = m;
                if (m > bv) { bv = m; bi = (unsigned)j; } // strict > => first index
            }
            best = ((unsigned long long)__float_as_uint(bv) << 32)
                 | (unsigned long long)(0xFFFFu - (unsigned)(tid * 16) - bi);
        }
        // wave64 max-reduce, 6 DPP steps (VALU pipe, no LDS)
        best = u64max(best, dpp64<0x111>(best));   // row_shr:1
        best = u64max(best, dpp64<0x112>(best));   // row_shr:2
        best = u64max(best, dpp64<0x114>(best));   // row_shr:4
        best = u64max(best, dpp64<0x118>(best));   // row_shr:8
        best = u64max(best, dpp64<0x142>(best));   // row_bcast:15
        best = u64max(best, dpp64<0x143>(best));   // row_bcast:31 -> lane63 = wave max
        if ((tid & 63) == 63) red[i & 1][tid >> 6] = best;
        __syncthreads();   // double-buffered red: one barrier per iter is race-free
        ulonglong2 ra = *(const ulonglong2*)&red[i & 1][0];
        ulonglong2 rb = *(const ulonglong2*)&red[i & 1][2];
        unsigned long long g = u64max(u64max(ra.x, ra.y), u64max(rb.x, rb.y));
        last = (int)(0xFFFFu - (unsigned)(g & 0xFFFFu));
    }
    __syncthreads();
    for (int i = tid; i < S_; i += 256) {    // bulk write-out (once)
        int o = b * S_ + i;
        float4 c = sP4[sSeq[i]];
        outCtr[o*3] = c.x; outCtr[o*3+1] = c.y; outCtr[o*3+2] = c.z;
        outBatch[o] = (float)b;
    }
}

// ---------------------------------------------------------------- radius-KNN (exact rank select)
__global__ __launch_bounds__(256) void k_nbr(const float* __restrict__ pos,
        const float* __restrict__ ctr, unsigned short* __restrict__ nbr,
        int* __restrict__ cnt, int* __restrict__ cntT) {
    __shared__ float cD[1024];
    __shared__ int   cI[1024];
    __shared__ int   cN;
    int q = blockIdx.x, tid = threadIdx.x;
    int b = q >> 11;
    if (tid == 0) cN = 0;
    __syncthreads();
    float cx = ctr[q*3], cy = ctr[q*3+1], cz = ctr[q*3+2];
    const float* P = pos + (size_t)b * N_ * 3;
    {
        #pragma clang fp contract(off)
        for (int j = tid; j < N_; j += 256) {
            float dx = cx - P[j*3], dy = cy - P[j*3+1], dz = cz - P[j*3+2];
            float d2 = (dx * dx + dy * dy) + dz * dz;
            if (d2 <= 0.04f) {                       // f32(0.2**2) boundary, exact
                int s = atomicAdd(&cN, 1);
                if (s < 1024) { cD[s] = d2; cI[s] = j; }
            }
        }
    }
    __syncthreads();
    int M = min(cN, 1024);
    int V = min(M, K_);
    for (int i = tid; i < M; i += 256) {
        float di = cD[i]; int ii = cI[i]; int r = 0;
        for (int j = 0; j < M; j++) {
            float dj = cD[j];
            r += (dj < di) || (dj == di && cI[j] < ii);   // stable top_k tie-break
        }
        if (r < K_) nbr[q * K_ + r] = (unsigned short)ii; // rank IS the slot: deterministic
    }
    if (tid == 0) { cnt[q] = V; atomicAdd(cntT, V); }
}

// ---------------------------------------------------------------- BN params
__global__ void k_bnparam(const unsigned long long* __restrict__ stats, const int* __restrict__ cntT,
        const float* __restrict__ g, const float* __restrict__ be,
        float* __restrict__ scale, float* __restrict__ shift) {
    int t = threadIdx.x;
    double c = (double)(*cntT);
    double mean = (double)(long long)stats[t] * (1.0 / 1048576.0) / c;
    double ex2  = (double)(long long)stats[128 + t] * (1.0 / 1048576.0) / c;
    double var = ex2 - mean * mean;
    if (var < 0.0) var = 0.0;
    double sc = (double)g[t] / sqrt(var + 1e-5);
    scale[t] = (float)sc;
    shift[t] = (float)((double)be[t] - mean * sc);
}

// ---------------------------------------------------------------- fused MLP pass (recompute pipeline)
// STAGE 0: gather+GEMM0 -> stats0
// STAGE 1: ... +BN0/ReLU+GEMM1 -> stats1
// STAGE 2: ... +BN1/ReLU+GEMM2 -> max->out
template<int STAGE>
__global__ __launch_bounds__(256) void k_mlp(const float* __restrict__ x,
        const float* __restrict__ pos, const float* __restrict__ ctr,
        const unsigned short* __restrict__ nbr, const int* __restrict__ cnt,
        const _Float16* __restrict__ w0t, const _Float16* __restrict__ w1t,
        const _Float16* __restrict__ w2t,
        const float* __restrict__ b0, const float* __restrict__ b1,
        const float* __restrict__ b2,
        const float* __restrict__ sc0, const float* __restrict__ sh0,
        const float* __restrict__ sc1, const float* __restrict__ sh1,
        unsigned long long* __restrict__ statsOut, float* __restrict__ outF) {
    __shared__ __align__(16) _Float16 sW0[128 * 104];
    __shared__ __align__(16) _Float16 sW1[(STAGE >= 1) ? 128 * 136 : 8];
    __shared__ __align__(16) _Float16 sW2[(STAGE >= 2) ? 128 * 136 : 8];
    __shared__ __align__(16) _Float16 sBuf[64 * 136];   // feat(104) / h'(136) stage
    __shared__ float sSum[(STAGE <= 1) ? 512 : 4];
    __shared__ float sSq [(STAGE <= 1) ? 512 : 4];
    __shared__ float sMax[(STAGE == 2) ? 512 : 4];
    __shared__ unsigned short sNbr[64];
    __shared__ float sB0v[128];
    __shared__ float sB1v[(STAGE >= 1) ? 128 : 4];
    __shared__ float sSc0[(STAGE >= 1) ? 128 : 4];
    __shared__ float sSh0[(STAGE >= 1) ? 128 : 4];
    __shared__ float sB2v[(STAGE >= 2) ? 128 : 4];
    __shared__ float sSc1[(STAGE >= 2) ? 128 : 4];
    __shared__ float sSh1[(STAGE >= 2) ? 128 : 4];

    int tid = threadIdx.x, wid = tid >> 6, lane = tid & 63;
    int lr = lane & 15, lq = lane >> 4;

    {   // stage W0T (stride 104 f16 = 52 dwords: conflict-spread)
        const unsigned* src = (const unsigned*)w0t;
        unsigned* dst = (unsigned*)sW0;
        for (int i = tid; i < 6144; i += 256) { int r = i / 48, c = i - r * 48; dst[r*52 + c] = src[i]; }
    }
    if constexpr (STAGE >= 1) {
        const unsigned* src = (const unsigned*)w1t;
        unsigned* dst = (unsigned*)sW1;
        for (int i = tid; i < 8192; i += 256) { int r = i >> 6, c = i & 63; dst[r*68 + c] = src[i]; }
    }
    if constexpr (STAGE >= 2) {
        const unsigned* src = (const unsigned*)w2t;
        unsigned* dst = (unsigned*)sW2;
        for (int i = tid; i < 8192; i += 256) { int r = i >> 6, c = i & 63; dst[r*68 + c] = src[i]; }
    }
    if (tid < 128) {
        sB0v[tid] = b0[tid];
        if constexpr (STAGE >= 1) { sB1v[tid] = b1[tid]; sSc0[tid] = sc0[tid]; sSh0[tid] = sh0[tid]; }
        if constexpr (STAGE >= 2) { sB2v[tid] = b2[tid]; sSc1[tid] = sc1[tid]; sSh1[tid] = sh1[tid]; }
    }
    if constexpr (STAGE <= 1)
        for (int i = tid; i < 512; i += 256) { sSum[i] = 0.f; sSq[i] = 0.f; }

    for (int qq = 0; qq < 8; qq++) {
        int q = blockIdx.x * 8 + qq;
        int b = q >> 11;
        __syncthreads();                    // prior-iter sBuf readers done
        int n = cnt[q];
        if (tid < 64) sNbr[tid] = nbr[q * K_ + tid];
        __syncthreads();
        {   // gather x_j -> feat cols 0..63 (f16), zero rows >= n
            int row = tid >> 2, c4 = (tid & 3) * 16;
            half8 o0, o1;
            #pragma unroll
            for (int e = 0; e < 8; e++) { o0[e] = (_Float16)0.f; o1[e] = (_Float16)0.f; }
            if (row < n) {
                const float4* xr = (const float4*)(x + ((size_t)b * N_ + sNbr[row]) * CIN + c4);
                float4 v0 = xr[0], v1 = xr[1], v2 = xr[2], v3 = xr[3];
                o0[0]=(_Float16)v0.x; o0[1]=(_Float16)v0.y; o0[2]=(_Float16)v0.z; o0[3]=(_Float16)v0.w;
                o0[4]=(_Float16)v1.x; o0[5]=(_Float16)v1.y; o0[6]=(_Float16)v1.z; o0[7]=(_Float16)v1.w;
                o1[0]=(_Float16)v2.x; o1[1]=(_Float16)v2.y; o1[2]=(_Float16)v2.z; o1[3]=(_Float16)v2.w;
                o1[4]=(_Float16)v3.x; o1[5]=(_Float16)v3.y; o1[6]=(_Float16)v3.z; o1[7]=(_Float16)v3.w;
            }
            *(half8*)&sBuf[row * 104 + c4]     = o0;
            *(half8*)&sBuf[row * 104 + c4 + 8] = o1;
        }
        if (tid < 64) {   // cols 64..66 = pos_j - ctr, 67..95 = 0
            half8 z, o;
            #pragma unroll
            for (int e = 0; e < 8; e++) { z[e] = (_Float16)0.f; o[e] = (_Float16)0.f; }
            if (tid < n) {
                int j = sNbr[tid];
                float cx = ctr[q*3], cy = ctr[q*3+1], cz = ctr[q*3+2];
                const float* pj = pos + ((size_t)b * N_ + j) * 3;
                o[0] = (_Float16)(pj[0] - cx); o[1] = (_Float16)(pj[1] - cy); o[2] = (_Float16)(pj[2] - cz);
            }
            *(half8*)&sBuf[tid * 104 + 64] = o;
            *(half8*)&sBuf[tid * 104 + 72] = z;
            *(half8*)&sBuf[tid * 104 + 80] = z;
            *(half8*)&sBuf[tid * 104 + 88] = z;
        }
        __syncthreads();

        // ---- GEMM0: K=96
        floatx4 acc[8];
        #pragma unroll
        for (int nt = 0; nt < 8; nt++)
            #pragma unroll
            for (int r = 0; r < 4; r++) acc[nt][r] = 0.f;
        #pragma unroll
        for (int ks = 0; ks < 3; ks++) {
            half8 av = *(const half8*)&sBuf[(wid * 16 + lr) * 104 + ks * 32 + lq * 8];
            #pragma unroll
            for (int nt = 0; nt < 8; nt++) {
                half8 bv = *(const half8*)&sW0[(nt * 16 + lr) * 104 + ks * 32 + lq * 8];
                acc[nt] = __builtin_amdgcn_mfma_f32_16x16x32_f16(av, bv, acc[nt], 0, 0, 0);
            }
        }
        __syncthreads();                    // all waves done reading feat
        int r0 = wid * 16 + lq * 4;

        if constexpr (STAGE == 0) {
            #pragma unroll
            for (int nt = 0; nt < 8; nt++) {
                int col = nt * 16 + lr;
                float bias = sB0v[col];
                float s1 = 0.f, s2 = 0.f;
                #pragma unroll
                for (int r = 0; r < 4; r++) {
                    float v = acc[nt][r] + bias;
                    if (r0 + r < n) { s1 += v; s2 += v * v; }
                }
                s1 += __shfl_xor(s1, 16); s1 += __shfl_xor(s1, 32);
                s2 += __shfl_xor(s2, 16); s2 += __shfl_xor(s2, 32);
                if (lq == 0) { sSum[wid * 128 + col] += s1; sSq[wid * 128 + col] += s2; }
            }
        } else {
            // BN0 + ReLU -> f16 A-matrix for GEMM1
            #pragma unroll
            for (int nt = 0; nt < 8; nt++) {
                int col = nt * 16 + lr;
                float bias = sB0v[col], s = sSc0[col], t2 = sSh0[col];
                #pragma unroll
                for (int r = 0; r < 4; r++) {
                    float v = (acc[nt][r] + bias) * s + t2;
                    sBuf[(r0 + r) * 136 + col] = (_Float16)fmaxf(v, 0.f);
                }
            }
            __syncthreads();
            // ---- GEMM1: K=128
            #pragma unroll
            for (int nt = 0; nt < 8; nt++)
                #pragma unroll
                for (int r = 0; r < 4; r++) acc[nt][r] = 0.f;
            #pragma unroll
            for (int ks = 0; ks < 4; ks++) {
                half8 av = *(const half8*)&sBuf[(wid * 16 + lr) * 136 + ks * 32 + lq * 8];
                #pragma unroll
                for (int nt = 0; nt < 8; nt++) {
                    half8 bv = *(const half8*)&sW1[(nt * 16 + lr) * 136 + ks * 32 + lq * 8];
                    acc[nt] = __builtin_amdgcn_mfma_f32_16x16x32_f16(av, bv, acc[nt], 0, 0, 0);
                }
            }
            __syncthreads();

            if constexpr (STAGE == 1) {
                #pragma unroll
                for (int nt = 0; nt < 8; nt++) {
                    int col = nt * 16 + lr;
                    float bias = sB1v[col];
                    float s1 = 0.f, s2 = 0.f;
                    #pragma unroll
                    for (int r = 0; r < 4; r++) {
                        float v = acc[nt][r] + bias;
                        if (r0 + r < n) { s1 += v; s2 += v * v; }
                    }
                    s1 += __shfl_xor(s1, 16); s1 += __shfl_xor(s1, 32);
                    s2 += __shfl_xor(s2, 16); s2 += __shfl_xor(s2, 32);
                    if (lq == 0) { sSum[wid * 128 + col] += s1; sSq[wid * 128 + col] += s2; }
                }
            } else {
                // BN1 + ReLU -> f16 A-matrix for GEMM2
                #pragma unroll
                for (int nt = 0; nt < 8; nt++) {
                    int col = nt * 16 + lr;
                    float bias = sB1v[col], s = sSc1[col], t2 = sSh1[col];
                    #pragma unroll
                    for (int r = 0; r < 4; r++) {
                        float v = (acc[nt][r] + bias) * s + t2;
                        sBuf[(r0 + r) * 136 + col] = (_Float16)fmaxf(v, 0.f);
                    }
                }
                __syncthreads();
                // ---- GEMM2: K=128
                #pragma unroll
                for (int nt = 0; nt < 8; nt++)
                    #pragma unroll
                    for (int r = 0; r < 4; r++) acc[nt][r] = 0.f;
                #pragma unroll
                for (int ks = 0; ks < 4; ks++) {
                    half8 av = *(const half8*)&sBuf[(wid * 16 + lr) * 136 + ks * 32 + lq * 8];
                    #pragma unroll
                    for (int nt = 0; nt < 8; nt++) {
                        half8 bv = *(const half8*)&sW2[(nt * 16 + lr) * 136 + ks * 32 + lq * 8];
                        acc[nt] = __builtin_amdgcn_mfma_f32_16x16x32_f16(av, bv, acc[nt], 0, 0, 0);
                    }
                }
                // masked max -> out
                #pragma unroll
                for (int nt = 0; nt < 8; nt++) {
                    int col = nt * 16 + lr;
                    float bias = sB2v[col];
                    float m = -__builtin_inff();
                    #pragma unroll
                    for (int r = 0; r < 4; r++)
                        if (r0 + r < n) m = fmaxf(m, acc[nt][r] + bias);
                    m = fmaxf(m, __shfl_xor(m, 16));
                    m = fmaxf(m, __shfl_xor(m, 32));
                    if (lq == 0) sMax[wid * 128 + col] = m;
                }
                __syncthreads();
                if (tid < 128) {
                    float m = fmaxf(fmaxf(sMax[tid], sMax[128 + tid]),
                                    fmaxf(sMax[256 + tid], sMax[384 + tid]));
                    outF[(size_t)q * 128 + tid] = m;
                }
            }
        }
    }
    if constexpr (STAGE <= 1) {
        __syncthreads();
        if (tid < 128) {   // fixed-point (2^20) i64 atomics: fast + deterministic
            float t1 = sSum[tid] + sSum[128 + tid] + sSum[256 + tid] + sSum[384 + tid];
            float t2 = sSq[tid] + sSq[128 + tid] + sSq[256 + tid] + sSq[384 + tid];
            atomicAdd(&statsOut[tid],       (unsigned long long)(long long)llrintf(t1 * 1048576.f));
            atomicAdd(&statsOut[128 + tid], (unsigned long long)(long long)llrintf(t2 * 1048576.f));
        }
    }
}

// ---------------------------------------------------------------- launch
extern "C" void kernel_launch(void* const* d_in, const int* in_sizes, int n_in,
                              void* d_out, int out_size, void* d_ws, size_t ws_size,
                              hipStream_t stream) {
    const float* x   = (const float*)d_in[0];
    const float* pos = (const float*)d_in[1];
    const float* W0  = (const float*)d_in[3];
    const float* b0  = (const float*)d_in[4];
    const float* g0  = (const float*)d_in[5];
    const float* be0 = (const float*)d_in[6];
    const float* W1  = (const float*)d_in[7];
    const float* b1  = (const float*)d_in[8];
    const float* g1  = (const float*)d_in[9];
    const float* be1 = (const float*)d_in[10];
    const float* W2  = (const float*)d_in[11];
    const float* b2  = (const float*)d_in[12];

    char* ws = (char*)d_ws;
    unsigned long long* stats = (unsigned long long*)(ws + WS_STATS);
    int* cntT = (int*)(ws + WS_CNTT);
    _Float16* w0t = (_Float16*)(ws + WS_W0T);
    _Float16* w1t = (_Float16*)(ws + WS_W1T);
    _Float16* w2t = (_Float16*)(ws + WS_W2T);
    float* sc0 = (float*)(ws + WS_SC0);
    float* sh0 = (float*)(ws + WS_SH0);
    float* sc1 = (float*)(ws + WS_SC1);
    float* sh1 = (float*)(ws + WS_SH1);
    int* cnt = (int*)(ws + WS_CNT);
    unsigned short* nbr = (unsigned short*)(ws + WS_NBR);

    float* outF = (float*)d_out;                  // [16384,128]
    float* outCtr = (float*)d_out + 2097152;      // [16384,3]
    float* outBatch = (float*)d_out + 2146304;    // [16384]

    k_prep<<<176, 256, 0, stream>>>(W0, W1, W2, w0t, w1t, w2t, stats, cntT);
    k_fps<<<B_, 256, 0, stream>>>(pos, outCtr, outBatch);
    k_nbr<<<Q_, 256, 0, stream>>>(pos, outCtr, nbr, cnt, cntT);
    k_mlp<0><<<Q_/8, 256, 0, stream>>>(x, pos, outCtr, nbr, cnt, w0t, w1t, w2t,
            b0, b1, b2, sc0, sh0, sc1, sh1, stats, outF);
    k_bnparam<<<1, 128, 0, stream>>>(stats, cntT, g0, be0, sc0, sh0);
    k_mlp<1><<<Q_/8, 256, 0, stream>>>(x, pos, outCtr, nbr, cnt, w0t, w1t, w2t,
            b0, b1, b2, sc0, sh0, sc1, sh1, stats + 256, outF);
    k_bnparam<<<1, 128, 0, stream>>>(stats + 256, cntT, g1, be1, sc1, sh1);
    k_mlp<2><<<Q_/8, 256, 0, stream>>>(x, pos, outCtr, nbr, cnt, w0t, w1t, w2t,
            b0, b1, b2, sc0, sh0, sc1, sh1, stats, outF);
}